// Round 1
// baseline (127.578 us; speedup 1.0000x reference)
//
#include <hip/hip_runtime.h>

#define HH 192
#define WW 192
#define VV 1024
#define FF 2048
#define NPIX (HH*WW)
#define SIG 0.01f
#define EPSF 1e-7f
#define LOG2E 1.4426950408889634f
#define CHUNK 128
#define NCHUNK (FF/CHUNK)

// ws layout (floats):
// [0, NPIX)                : per-pixel log2-miss accumulator (zeroed each call)
// [NPIX, NPIX + FF*12)     : per-face edge coefficients (12 floats/face, 9 used)
// [NPIX + FF*12]           : loss scale factor (1 + distance penalty)

__global__ void __launch_bounds__(256)
prep_kernel(const float* __restrict__ verts, const int* __restrict__ faces,
            const float* __restrict__ cam, float* __restrict__ coeffs,
            float* __restrict__ factor_out) {
    __shared__ float sx[VV], sy[VV];
    const int tid = threadIdx.x;
    const float cx = cam[0], cy = cam[1], cz = cam[2];
    // z_axis = normalize(-eye)
    const float nrm = sqrtf(cx*cx + cy*cy + cz*cz);
    const float inv = 1.0f / fmaxf(nrm, 1e-8f);
    const float zx = -cx*inv, zy = -cy*inv, zz = -cz*inv;
    // x_axis = normalize(cross((0,1,0), z)) = normalize((zz, 0, -zx))
    float xx = zz, xz = -zx;
    const float invx = 1.0f / fmaxf(sqrtf(xx*xx + xz*xz), 1e-8f);
    xx *= invx; xz *= invx;
    // y_axis = cross(z, x)  (x_axis.y == 0)
    const float yx = zy*xz;
    const float yy = zz*xx - zx*xz;
    const float yz = -zy*xx;
    const float ratio = 0.57735026918962576f;  // tan(30 deg)

    for (int i = tid; i < VV; i += 256) {
        const float vx = verts[3*i+0] - cx;
        const float vy = verts[3*i+1] - cy;
        const float vz = verts[3*i+2] - cz;
        const float pcx = xx*vx + xz*vz;
        const float pcy = yx*vx + yy*vy + yz*vz;
        float pcz = zx*vx + zy*vy + zz*vz;
        pcz = fmaxf(pcz, 1e-5f);
        const float iz = 1.0f / (pcz * ratio);
        sx[i] = pcx * iz;
        sy[i] = pcy * iz;
    }
    __syncthreads();

    for (int f = tid; f < FF; f += 256) {
        const int i0 = faces[3*f+0], i1 = faces[3*f+1], i2 = faces[3*f+2];
        const float p0x = sx[i0], p0y = sy[i0];
        const float p1x = sx[i1], p1y = sy[i1];
        const float p2x = sx[i2], p2y = sy[i2];
        const float e0x = p1x-p0x, e0y = p1y-p0y;
        const float e1x = p2x-p1x, e1y = p2y-p1y;
        const float e2x = p0x-p2x, e2y = p0y-p2y;
        const float c0 = e0y*p0x - e0x*p0y;
        const float c1 = e1y*p1x - e1x*p1y;
        const float c2 = e2y*p2x - e2x*p2y;
        // area2 = (p1-p0) x (p2-p0)
        const float area2 = e0x*(p2y-p0y) - e0y*(p2x-p0x);
        const float sgn = (area2 >= 0.0f) ? 1.0f : -1.0f;
        const float l0 = fmaxf(sqrtf(e0x*e0x + e0y*e0y), 1e-8f);
        const float l1 = fmaxf(sqrtf(e1x*e1x + e1y*e1y), 1e-8f);
        const float l2 = fmaxf(sqrtf(e2x*e2x + e2y*e2y), 1e-8f);
        // t_i = exp2(m_i * (e.x*py - e.y*px + c));  sigmoid(d/SIG) = 1/(1+t_i)
        const float m0 = -sgn * (LOG2E/SIG) / l0;
        const float m1 = -sgn * (LOG2E/SIG) / l1;
        const float m2 = -sgn * (LOG2E/SIG) / l2;
        float* o = coeffs + f*12;
        o[0] = m0*e0x;  o[1] = -m0*e0y;  o[2]  = m0*c0;
        o[3] = m1*e1x;  o[4] = -m1*e1y;  o[5]  = m1*c1;
        o[6] = m2*e2x;  o[7] = -m2*e2y;  o[8]  = m2*c2;
        o[9] = 0.0f;    o[10] = 0.0f;    o[11] = 0.0f;
    }
    if (tid == 0) {
        const float dist = sqrtf(cx*cx + cy*cy + cz*cz);
        *factor_out = 1.0f + fmaxf(6.0f - dist, 0.0f);
    }
}

__global__ void __launch_bounds__(256)
pair_kernel(const float* __restrict__ coeffs, float* __restrict__ logmiss) {
    const int p = blockIdx.x * 256 + threadIdx.x;
    const int y = p / WW;
    const int x = p - y * WW;
    const float px = (x + 0.5f) * (2.0f/WW) - 1.0f;
    const float py = 1.0f - (y + 0.5f) * (2.0f/HH);
    const float* __restrict__ base = coeffs + (size_t)blockIdx.y * CHUNK * 12;
    float acc = 0.0f;
    #pragma unroll 4
    for (int f = 0; f < CHUNK; ++f) {
        const float* o = base + f*12;
        const float t0 = __builtin_amdgcn_exp2f(fmaf(o[0], py, fmaf(o[1], px, o[2])));
        const float t1 = __builtin_amdgcn_exp2f(fmaf(o[3], py, fmaf(o[4], px, o[5])));
        const float t2 = __builtin_amdgcn_exp2f(fmaf(o[6], py, fmaf(o[7], px, o[8])));
        const float P = (1.0f + t0) * (1.0f + t1) * (1.0f + t2);
        const float inside = __builtin_amdgcn_rcpf(P);     // sigmoid product
        acc += __builtin_amdgcn_logf((1.0f + EPSF) - inside);  // log2 domain
    }
    atomicAdd(&logmiss[p], acc);
}

__global__ void __launch_bounds__(256)
loss_kernel(const float* __restrict__ logmiss, const float* __restrict__ ref,
            const float* __restrict__ factor, float* __restrict__ out) {
    const int p = blockIdx.x * 256 + threadIdx.x;
    const float s = logmiss[p];                      // sum of log2(1-inside+eps)
    const float image = 1.0f - __builtin_amdgcn_exp2f(s);
    const float d = ref[p] - image;
    float sq = d * d;
    #pragma unroll
    for (int off = 32; off > 0; off >>= 1)
        sq += __shfl_down(sq, off, 64);
    __shared__ float wsum[4];
    const int lane = threadIdx.x & 63, wave = threadIdx.x >> 6;
    if (lane == 0) wsum[wave] = sq;
    __syncthreads();
    if (threadIdx.x == 0) {
        const float tot = (wsum[0] + wsum[1] + wsum[2] + wsum[3]) * factor[0];
        atomicAdd(out, tot);
    }
}

extern "C" void kernel_launch(void* const* d_in, const int* in_sizes, int n_in,
                              void* d_out, int out_size, void* d_ws, size_t ws_size,
                              hipStream_t stream) {
    const float* verts = (const float*)d_in[0];   // (1,1024,3) f32
    const int*   faces = (const int*)d_in[1];     // (1,2048,3) i32
    const float* ref   = (const float*)d_in[2];   // (192,192) f32
    const float* cam   = (const float*)d_in[3];   // (3,) f32
    float* out = (float*)d_out;

    float* ws      = (float*)d_ws;
    float* logmiss = ws;                    // NPIX floats
    float* coeffs  = ws + NPIX;             // FF*12 floats
    float* factor  = ws + NPIX + FF*12;     // 1 float

    hipMemsetAsync(d_out, 0, sizeof(float), stream);
    hipMemsetAsync(logmiss, 0, NPIX * sizeof(float), stream);

    prep_kernel<<<1, 256, 0, stream>>>(verts, faces, cam, coeffs, factor);
    pair_kernel<<<dim3(NPIX/256, NCHUNK), 256, 0, stream>>>(coeffs, logmiss);
    loss_kernel<<<NPIX/256, 256, 0, stream>>>(logmiss, ref, factor, out);
}

// Round 2
// 100.150 us; speedup vs baseline: 1.2739x; 1.2739x over previous
//
#include <hip/hip_runtime.h>

#define HH 192
#define WW 192
#define VV 1024
#define FF 2048
#define NPIX (HH*WW)
#define SIG 0.01f
#define EPSF 1e-7f
#define LOG2E 1.4426950408889634f
#define CHUNK 64
#define NCHUNK (FF/CHUNK)
#define BAND_T 15.0f                 // |arg| threshold (log2 units) for the soft band
#define DIL 0.115f                   // outer-line shift (> BAND_T*SIG/LOG2E = 0.10397)
#define C_OUT 1.4426943e-7f          // log2(1+EPSF)
#define C_IN  (-23.2534966642f)      // log2(EPSF)

// ws layout (floats):
// [0, NPIX)                          per-pixel log2-miss accumulator (swizzled 8x8-tile order)
// [NPIX, NPIX+FF*12)                 per-face edge coefficients (9 used, stride 12)
// [NPIX+FF*12, NPIX+FF*12+FF*4)      per-face conservative bbox (xmin,xmax,ymin,ymax)
// [NPIX+FF*16]                       loss scale factor

__global__ void __launch_bounds__(256)
prep_kernel(const float* __restrict__ verts, const int* __restrict__ faces,
            const float* __restrict__ cam, float* __restrict__ coeffs,
            float* __restrict__ bbox, float* __restrict__ factor_out,
            float* __restrict__ logmiss, float* __restrict__ out) {
    const int tid = threadIdx.x;
    if (blockIdx.x < NPIX / 256) {          // zeroing blocks
        logmiss[blockIdx.x * 256 + tid] = 0.0f;
        return;
    }
    // block NPIX/256 does the real prep
    __shared__ float sx[VV], sy[VV];
    const float cx = cam[0], cy = cam[1], cz = cam[2];
    const float nrm = sqrtf(cx*cx + cy*cy + cz*cz);
    const float inv = 1.0f / fmaxf(nrm, 1e-8f);
    const float zx = -cx*inv, zy = -cy*inv, zz = -cz*inv;
    float xx = zz, xz = -zx;
    const float invx = 1.0f / fmaxf(sqrtf(xx*xx + xz*xz), 1e-8f);
    xx *= invx; xz *= invx;
    const float yx = zy*xz;
    const float yy = zz*xx - zx*xz;
    const float yz = -zy*xx;
    const float ratio = 0.57735026918962576f;  // tan(30 deg)

    for (int i = tid; i < VV; i += 256) {
        const float vx = verts[3*i+0] - cx;
        const float vy = verts[3*i+1] - cy;
        const float vz = verts[3*i+2] - cz;
        const float pcx = xx*vx + xz*vz;
        const float pcy = yx*vx + yy*vy + yz*vz;
        float pcz = zx*vx + zy*vy + zz*vz;
        pcz = fmaxf(pcz, 1e-5f);
        const float iz = 1.0f / (pcz * ratio);
        sx[i] = pcx * iz;
        sy[i] = pcy * iz;
    }
    __syncthreads();

    for (int f = tid; f < FF; f += 256) {
        const int i0 = faces[3*f+0], i1 = faces[3*f+1], i2 = faces[3*f+2];
        const float p0x = sx[i0], p0y = sy[i0];
        const float p1x = sx[i1], p1y = sy[i1];
        const float p2x = sx[i2], p2y = sy[i2];
        const float e0x = p1x-p0x, e0y = p1y-p0y;
        const float e1x = p2x-p1x, e1y = p2y-p1y;
        const float e2x = p0x-p2x, e2y = p0y-p2y;
        const float c0 = e0y*p0x - e0x*p0y;
        const float c1 = e1y*p1x - e1x*p1y;
        const float c2 = e2y*p2x - e2x*p2y;
        const float area2 = e0x*(p2y-p0y) - e0y*(p2x-p0x);
        const float sgn = (area2 >= 0.0f) ? 1.0f : -1.0f;
        const float l0 = fmaxf(sqrtf(e0x*e0x + e0y*e0y), 1e-8f);
        const float l1 = fmaxf(sqrtf(e1x*e1x + e1y*e1y), 1e-8f);
        const float l2 = fmaxf(sqrtf(e2x*e2x + e2y*e2y), 1e-8f);
        // signed distance (positive inside): d_i = nx_i*px + ny_i*py - o_i
        const float s0 = sgn / l0, s1 = sgn / l1, s2 = sgn / l2;
        const float nx0 = -e0y*s0, ny0 = e0x*s0, o0 = -c0*s0;
        const float nx1 = -e1y*s1, ny1 = e1x*s1, o1 = -c1*s1;
        const float nx2 = -e2y*s2, ny2 = e2x*s2, o2 = -c2*s2;
        // arg_i = -d_i * LOG2E/SIG ; t_i = 2^arg_i ; sigmoid = 1/(1+t_i)
        const float k = -(LOG2E / SIG);
        float* o = coeffs + f*12;
        o[0] = k*ny0;  o[1] = k*nx0;  o[2] = -k*o0;
        o[3] = k*ny1;  o[4] = k*nx1;  o[5] = -k*o1;
        o[6] = k*ny2;  o[7] = k*nx2;  o[8] = -k*o2;
        o[9] = 0.f; o[10] = 0.f; o[11] = 0.f;
        // outer-triangle bbox: intersect lines n_i . p = o_i - DIL pairwise
        const float q0 = o0 - DIL, q1 = o1 - DIL, q2 = o2 - DIL;
        float X[3], Y[3];
        {   const float det = nx0*ny1 - ny0*nx1, r = 1.0f/det;
            X[0] = (q0*ny1 - q1*ny0)*r;  Y[0] = (nx0*q1 - nx1*q0)*r; }
        {   const float det = nx1*ny2 - ny1*nx2, r = 1.0f/det;
            X[1] = (q1*ny2 - q2*ny1)*r;  Y[1] = (nx1*q2 - nx2*q1)*r; }
        {   const float det = nx2*ny0 - ny2*nx0, r = 1.0f/det;
            X[2] = (q2*ny0 - q0*ny2)*r;  Y[2] = (nx2*q0 - nx0*q2)*r; }
        float bxmin = fminf(fminf(X[0],X[1]),X[2]) - 1e-3f;
        float bxmax = fmaxf(fmaxf(X[0],X[1]),X[2]) + 1e-3f;
        float bymin = fminf(fminf(Y[0],Y[1]),Y[2]) - 1e-3f;
        float bymax = fmaxf(fmaxf(Y[0],Y[1]),Y[2]) + 1e-3f;
        bool ok = (X[0]==X[0]) && (X[1]==X[1]) && (X[2]==X[2])
               && (Y[0]==Y[0]) && (Y[1]==Y[1]) && (Y[2]==Y[2]);
        if (!ok) { bxmin = -1e30f; bxmax = 1e30f; bymin = -1e30f; bymax = 1e30f; }
        float* bb = bbox + f*4;
        bb[0] = bxmin; bb[1] = bxmax; bb[2] = bymin; bb[3] = bymax;
    }
    if (tid == 0) {
        const float dist = sqrtf(cx*cx + cy*cy + cz*cz);
        *factor_out = 1.0f + fmaxf(6.0f - dist, 0.0f);
        *out = 0.0f;
    }
}

__global__ void __launch_bounds__(256)
pair_kernel(const float* __restrict__ coeffs, const float* __restrict__ bbox,
            float* __restrict__ logmiss) {
    const int tid = threadIdx.x;
    const int bx = blockIdx.x;                // 0..143, covers 4 tiles = 32x8 px
    // block pixel region in screen coords
    const int tile0 = 4 * bx;
    const int tr = tile0 / 24, tc0 = tile0 % 24;
    const float rxmin = (tc0*8 + 0.5f) * (2.0f/WW) - 1.0f;
    const float rxmax = (tc0*8 + 31.5f) * (2.0f/WW) - 1.0f;
    const float rymax = 1.0f - (tr*8 + 0.5f) * (2.0f/HH);
    const float rymin = 1.0f - (tr*8 + 7.5f) * (2.0f/HH);

    __shared__ int s_cnt;
    __shared__ int s_list[CHUNK];
    if (tid == 0) s_cnt = 0;
    __syncthreads();
    if (tid < CHUNK) {
        const int f = blockIdx.y * CHUNK + tid;
        const float4 bb = reinterpret_cast<const float4*>(bbox)[f];
        const bool keep = !(bb.x > rxmax || bb.y < rxmin || bb.z > rymax || bb.w < rymin);
        if (keep) { const int slot = atomicAdd(&s_cnt, 1); s_list[slot] = f; }
    }
    __syncthreads();
    const int K = s_cnt;

    // pixel for this lane: wave = one 8x8 tile
    const int p = bx * 256 + tid;
    const int w = p >> 6, l = p & 63;
    const int x = (w % 24) * 8 + (l & 7);
    const int y = (w / 24) * 8 + (l >> 3);
    const float px = (x + 0.5f) * (2.0f/WW) - 1.0f;
    const float py = 1.0f - (y + 0.5f) * (2.0f/HH);

    float acc = CHUNK * C_OUT;   // baseline: every face contributes log2(1+eps)
    for (int j = 0; j < K; ++j) {
        const int f = __builtin_amdgcn_readfirstlane(s_list[j]);
        const float* o = coeffs + f*12;
        const float a0 = fmaf(o[0], py, fmaf(o[1], px, o[2]));
        const float a1 = fmaf(o[3], py, fmaf(o[4], px, o[5]));
        const float a2 = fmaf(o[6], py, fmaf(o[7], px, o[8]));
        const float m = fmaxf(fmaxf(a0, a1), a2);
        if (m < BAND_T) {
            float d = C_IN - C_OUT;                 // deep inside
            if (m > -BAND_T) {                      // soft band: full evaluation
                const float t0 = __builtin_amdgcn_exp2f(a0);
                const float t1 = __builtin_amdgcn_exp2f(a1);
                const float t2 = __builtin_amdgcn_exp2f(a2);
                const float P = (1.0f + t0) * (1.0f + t1) * (1.0f + t2);
                const float inside = __builtin_amdgcn_rcpf(P);
                d = __builtin_amdgcn_logf((1.0f + EPSF) - inside) - C_OUT;
            }
            acc += d;
        }
    }
    atomicAdd(&logmiss[p], acc);
}

__global__ void __launch_bounds__(256)
loss_kernel(const float* __restrict__ logmiss, const float* __restrict__ ref,
            const float* __restrict__ factor, float* __restrict__ out) {
    const int p = blockIdx.x * 256 + threadIdx.x;
    const int w = p >> 6, l = p & 63;
    const int x = (w % 24) * 8 + (l & 7);
    const int y = (w / 24) * 8 + (l >> 3);
    const float s = logmiss[p];
    const float image = 1.0f - __builtin_amdgcn_exp2f(s);
    const float d = ref[y*WW + x] - image;
    float sq = d * d;
    #pragma unroll
    for (int off = 32; off > 0; off >>= 1)
        sq += __shfl_down(sq, off, 64);
    __shared__ float wsum[4];
    const int lane = threadIdx.x & 63, wave = threadIdx.x >> 6;
    if (lane == 0) wsum[wave] = sq;
    __syncthreads();
    if (threadIdx.x == 0) {
        const float tot = (wsum[0] + wsum[1] + wsum[2] + wsum[3]) * factor[0];
        atomicAdd(out, tot);
    }
}

extern "C" void kernel_launch(void* const* d_in, const int* in_sizes, int n_in,
                              void* d_out, int out_size, void* d_ws, size_t ws_size,
                              hipStream_t stream) {
    const float* verts = (const float*)d_in[0];   // (1,1024,3) f32
    const int*   faces = (const int*)d_in[1];     // (1,2048,3) i32
    const float* ref   = (const float*)d_in[2];   // (192,192) f32
    const float* cam   = (const float*)d_in[3];   // (3,) f32
    float* out = (float*)d_out;

    float* ws      = (float*)d_ws;
    float* logmiss = ws;                       // NPIX
    float* coeffs  = ws + NPIX;                // FF*12
    float* bboxes  = ws + NPIX + FF*12;        // FF*4
    float* factor  = ws + NPIX + FF*16;        // 1

    prep_kernel<<<NPIX/256 + 1, 256, 0, stream>>>(verts, faces, cam, coeffs,
                                                  bboxes, factor, logmiss, out);
    pair_kernel<<<dim3(NPIX/256, NCHUNK), 256, 0, stream>>>(coeffs, bboxes, logmiss);
    loss_kernel<<<NPIX/256, 256, 0, stream>>>(logmiss, ref, factor, out);
}